// Round 1
// baseline (242.218 us; speedup 1.0000x reference)
//
#include <hip/hip_runtime.h>

typedef __attribute__((ext_vector_type(8))) __bf16 bf16x8;
typedef __attribute__((ext_vector_type(4))) float f32x4;
typedef __attribute__((ext_vector_type(8))) unsigned short ushort8;

typedef const __attribute__((address_space(1))) unsigned int gq_t;
typedef __attribute__((address_space(3))) unsigned int lq_t;

// RNE float -> bf16 (finite inputs)
__device__ __forceinline__ unsigned short f2bf(float f) {
  unsigned int u = __builtin_bit_cast(unsigned int, f);
  u += 0x7fffu + ((u >> 16) & 1u);
  return (unsigned short)(u >> 16);
}

// ---------------- convert x: fp32 [M*K] -> bf16 ----------------
__global__ void cvt_x_kernel(const float* __restrict__ x, ushort8* __restrict__ o, int n8) {
  int stride = gridDim.x * blockDim.x;
  for (int i = blockIdx.x * blockDim.x + threadIdx.x; i < n8; i += stride) {
    const float4* p = (const float4*)(x) + 2 * (size_t)i;
    float4 v0 = p[0], v1 = p[1];
    ushort8 r;
    r[0] = f2bf(v0.x); r[1] = f2bf(v0.y); r[2] = f2bf(v0.z); r[3] = f2bf(v0.w);
    r[4] = f2bf(v1.x); r[5] = f2bf(v1.y); r[6] = f2bf(v1.z); r[7] = f2bf(v1.w);
    o[i] = r;
  }
}

// ------- convert weight: fp32 [N][K] * scale[n] -> bf16 --------
__global__ void cvt_w_kernel(const float* __restrict__ w, const float* __restrict__ scale,
                             ushort8* __restrict__ o, int n8, int k8) {
  int stride = gridDim.x * blockDim.x;
  for (int i = blockIdx.x * blockDim.x + threadIdx.x; i < n8; i += stride) {
    float s = scale[i / k8];
    const float4* p = (const float4*)(w) + 2 * (size_t)i;
    float4 v0 = p[0], v1 = p[1];
    ushort8 r;
    r[0] = f2bf(v0.x * s); r[1] = f2bf(v0.y * s); r[2] = f2bf(v0.z * s); r[3] = f2bf(v0.w * s);
    r[4] = f2bf(v1.x * s); r[5] = f2bf(v1.y * s); r[6] = f2bf(v1.z * s); r[7] = f2bf(v1.w * s);
    o[i] = r;
  }
}

// ---------------- main GEMM: C = A * B^T + bias ----------------
// A: bf16 [M][K] row-major, B: bf16 [N][K] row-major (B^T form), C: fp32 [M][N]
// 128x128 tile, BK=64, 4 waves (2x2), each wave 64x64 out (4x4 frags of 16x16x32 MFMA).
#define BM 128
#define BN 128
#define BK 64

__global__ __launch_bounds__(256) void gemm_bt_bias_kernel(
    const unsigned short* __restrict__ A, const unsigned short* __restrict__ B,
    const float* __restrict__ bias, float* __restrict__ C, int M, int N, int K) {
  __shared__ unsigned short a_lds[BM * BK];
  __shared__ unsigned short b_lds[BN * BK];

  const int nbn = N / BN;
  const int nwg = (M / BM) * nbn;
  int bid = blockIdx.x;
  if ((nwg & 7) == 0) {            // XCD-aware swizzle (bijective when nwg%8==0)
    int q = nwg >> 3;
    bid = (bid & 7) * q + (bid >> 3);
  }
  const int brow = bid / nbn;
  const int bcol = bid % nbn;

  const int tid = threadIdx.x;
  const int lane = tid & 63;
  const int wid = tid >> 6;
  const int wr = wid >> 1;
  const int wc = wid & 1;

  // staging: each thread stages 8 bf16 (16B) per issue; 4 issues each for A and B
  const unsigned short* a_src = A + (size_t)(brow * BM + (tid >> 3)) * K + ((tid & 7) << 3);
  const unsigned short* b_src = B + (size_t)(bcol * BN + (tid >> 3)) * K + ((tid & 7) << 3);
  unsigned short* a_dst = a_lds + tid * 8;   // linear: dest = wave-uniform base + lane*16B
  unsigned short* b_dst = b_lds + tid * 8;

  f32x4 acc[4][4];
#pragma unroll
  for (int m = 0; m < 4; ++m)
#pragma unroll
    for (int n = 0; n < 4; ++n) acc[m][n] = (f32x4){0.f, 0.f, 0.f, 0.f};

  // fragment read base: lane l holds 8 contiguous K-elems of row (l&15), k-off (l>>4)*8
  const int frow = lane & 15;
  const int fk = (lane >> 4) << 3;
  const unsigned short* a_rd = a_lds + (wr * 64 + frow) * BK + fk;
  const unsigned short* b_rd = b_lds + (wc * 64 + frow) * BK + fk;

  for (int k0 = 0; k0 < K; k0 += BK) {
#pragma unroll
    for (int i = 0; i < 4; ++i) {
      __builtin_amdgcn_global_load_lds((gq_t*)(a_src + k0 + (size_t)i * 32 * K),
                                       (lq_t*)(a_dst + i * 2048), 16, 0, 0);
      __builtin_amdgcn_global_load_lds((gq_t*)(b_src + k0 + (size_t)i * 32 * K),
                                       (lq_t*)(b_dst + i * 2048), 16, 0, 0);
    }
    __syncthreads();   // compiler drains vmcnt(0) before s_barrier
#pragma unroll
    for (int kk = 0; kk < 2; ++kk) {
      bf16x8 af[4], bg[4];
#pragma unroll
      for (int m = 0; m < 4; ++m)
        af[m] = *(const bf16x8*)(a_rd + m * 16 * BK + kk * 32);
#pragma unroll
      for (int n = 0; n < 4; ++n)
        bg[n] = *(const bf16x8*)(b_rd + n * 16 * BK + kk * 32);
#pragma unroll
      for (int m = 0; m < 4; ++m)
#pragma unroll
        for (int n = 0; n < 4; ++n)
          acc[m][n] = __builtin_amdgcn_mfma_f32_16x16x32_bf16(af[m], bg[n], acc[m][n], 0, 0, 0);
    }
    __syncthreads();
  }

  // epilogue: C/D mapping col=lane&15, row=(lane>>4)*4+reg  [measured m89/m91]
  const int crow0 = brow * BM + wr * 64 + ((lane >> 4) << 2);
  const int ccol0 = bcol * BN + wc * 64 + (lane & 15);
  float bv[4];
#pragma unroll
  for (int n = 0; n < 4; ++n) bv[n] = bias[ccol0 + n * 16];
#pragma unroll
  for (int m = 0; m < 4; ++m) {
#pragma unroll
    for (int r = 0; r < 4; ++r) {
      float* crow = C + (size_t)(crow0 + m * 16 + r) * N;
#pragma unroll
      for (int n = 0; n < 4; ++n)
        crow[ccol0 + n * 16] = acc[m][n][r] + bv[n];
    }
  }
}

// ---------- fallback (only if ws too small / odd shapes): fp32 tiled ----------
__global__ void gemm_fallback_kernel(const float* __restrict__ X, const float* __restrict__ W,
                                     const float* __restrict__ scale, const float* __restrict__ bias,
                                     float* __restrict__ out, int M, int N, int K) {
  __shared__ float as[64][33];
  __shared__ float bs[64][33];
  int tx = threadIdx.x & 15, ty = threadIdx.x >> 4;
  int brow = blockIdx.y * 64, bcol = blockIdx.x * 64;
  float acc[4][4] = {};
  for (int k0 = 0; k0 < K; k0 += 32) {
    int kw = (K - k0 < 32) ? (K - k0) : 32;
    for (int i = 0; i < 8; ++i) {
      int idx = (int)threadIdx.x + i * 256;
      int r = idx >> 5, c = idx & 31;
      int ga = brow + r, gb = bcol + r;
      as[r][c] = (ga < M && c < kw) ? X[(size_t)ga * K + k0 + c] : 0.f;
      bs[r][c] = (gb < N && c < kw) ? W[(size_t)gb * K + k0 + c] * scale[gb] : 0.f;
    }
    __syncthreads();
    for (int k = 0; k < 32; ++k)
#pragma unroll
      for (int i = 0; i < 4; ++i)
#pragma unroll
        for (int j = 0; j < 4; ++j)
          acc[i][j] += as[ty * 4 + i][k] * bs[tx * 4 + j][k];
    __syncthreads();
  }
  for (int i = 0; i < 4; ++i) {
    int r = brow + ty * 4 + i;
    if (r >= M) continue;
    for (int j = 0; j < 4; ++j) {
      int c = bcol + tx * 4 + j;
      if (c < N) out[(size_t)r * N + c] = acc[i][j] + bias[c];
    }
  }
}

extern "C" void kernel_launch(void* const* d_in, const int* in_sizes, int n_in,
                              void* d_out, int out_size, void* d_ws, size_t ws_size,
                              hipStream_t stream) {
  const float* x     = (const float*)d_in[0];
  const float* w     = (const float*)d_in[1];
  const float* scale = (const float*)d_in[2];
  const float* bias  = (const float*)d_in[3];
  float* out = (float*)d_out;

  const long N = in_sizes[2];               // D_OUT
  const long K = in_sizes[1] / N;           // D_IN
  const long M = (long)in_sizes[0] / K;     // B*S

  const size_t need = ((size_t)M * K + (size_t)N * K) * sizeof(unsigned short);
  const bool ok = (ws_size >= need) && (M % BM == 0) && (N % BN == 0) && (K % BK == 0) && (K % 8 == 0);

  if (ok) {
    unsigned short* xa = (unsigned short*)d_ws;
    unsigned short* wb = xa + (size_t)M * K;
    int n8x = (int)((size_t)M * K / 8);
    int n8w = (int)((size_t)N * K / 8);
    cvt_x_kernel<<<2048, 256, 0, stream>>>(x, (ushort8*)xa, n8x);
    cvt_w_kernel<<<1024, 256, 0, stream>>>(w, scale, (ushort8*)wb, n8w, (int)(K / 8));
    int nwg = (int)((M / BM) * (N / BN));
    gemm_bt_bias_kernel<<<nwg, 256, 0, stream>>>(xa, wb, bias, out, (int)M, (int)N, (int)K);
  } else {
    dim3 grid((unsigned)((N + 63) / 64), (unsigned)((M + 63) / 64));
    gemm_fallback_kernel<<<grid, 256, 0, stream>>>(x, w, scale, bias, out, (int)M, (int)N, (int)K);
  }
}

// Round 2
// 175.967 us; speedup vs baseline: 1.3765x; 1.3765x over previous
//
#include <hip/hip_runtime.h>

typedef __attribute__((ext_vector_type(8))) __bf16 bf16x8;
typedef __attribute__((ext_vector_type(4))) float f32x4;
typedef __attribute__((ext_vector_type(8))) unsigned short ushort8;
typedef const __attribute__((address_space(1))) unsigned int gq_t;
typedef __attribute__((address_space(3))) unsigned int lq_t;

// RNE float -> bf16 (finite inputs)
__device__ __forceinline__ unsigned short f2bf(float f) {
  unsigned int u = __builtin_bit_cast(unsigned int, f);
  u += 0x7fffu + ((u >> 16) & 1u);
  return (unsigned short)(u >> 16);
}

// ---------------- convert x: fp32 [M*K] -> bf16 ----------------
__global__ void cvt_x_kernel(const float* __restrict__ x, ushort8* __restrict__ o, int n8) {
  int stride = gridDim.x * blockDim.x;
  for (int i = blockIdx.x * blockDim.x + threadIdx.x; i < n8; i += stride) {
    const float4* p = (const float4*)(x) + 2 * (size_t)i;
    float4 v0 = p[0], v1 = p[1];
    ushort8 r;
    r[0] = f2bf(v0.x); r[1] = f2bf(v0.y); r[2] = f2bf(v0.z); r[3] = f2bf(v0.w);
    r[4] = f2bf(v1.x); r[5] = f2bf(v1.y); r[6] = f2bf(v1.z); r[7] = f2bf(v1.w);
    o[i] = r;
  }
}

// ------- convert weight: fp32 [N][K] * scale[n] -> bf16 --------
__global__ void cvt_w_kernel(const float* __restrict__ w, const float* __restrict__ scale,
                             ushort8* __restrict__ o, int n8, int k8) {
  int stride = gridDim.x * blockDim.x;
  for (int i = blockIdx.x * blockDim.x + threadIdx.x; i < n8; i += stride) {
    float s = scale[i / k8];
    const float4* p = (const float4*)(w) + 2 * (size_t)i;
    float4 v0 = p[0], v1 = p[1];
    ushort8 r;
    r[0] = f2bf(v0.x * s); r[1] = f2bf(v0.y * s); r[2] = f2bf(v0.z * s); r[3] = f2bf(v0.w * s);
    r[4] = f2bf(v1.x * s); r[5] = f2bf(v1.y * s); r[6] = f2bf(v1.z * s); r[7] = f2bf(v1.w * s);
    o[i] = r;
  }
}

// =================== 256x256 8-phase GEMM ===================
// C = A * B^T + bias.  A: bf16 [M][K], B: bf16 [N][K], C: fp32 [M][N].
// 8 waves (2 wr x 4 wc), BK=64, 128 KiB dynamic LDS:
//   per buffer (64 KiB): [A-mh0 16K][A-mh1 16K][B-nh0 16K][B-nh1 16K]
//   A-mh unit rows (phys p 0..127): wr = p>>6, m&3 = (p>>4)&3  -> tile row = (p>>6)*128 + mh*64 + (p&63)
//   B-nh unit rows: wc = p>>5                                   -> tile row = (p>>5)*64 + nh*32 + (p&31)
// XOR swizzle within each 128B row: byte ^= ((row&7)<<4), applied on the
// pre-swizzled GLOBAL source (linear LDS dest for global_load_lds) + on reads.

#define FENCE asm volatile("" ::: "memory")
#define BARRIER do { FENCE; __builtin_amdgcn_s_barrier(); FENCE; } while (0)
#define WAITV4 asm volatile("s_waitcnt vmcnt(4)" ::: "memory")
#define WAITV0 asm volatile("s_waitcnt vmcnt(0)" ::: "memory")

#define QUAD(MH, NH)                                                                     \
  do {                                                                                   \
    __builtin_amdgcn_s_setprio(1);                                                       \
    _Pragma("unroll") for (int mm = 0; mm < 4; ++mm) {                                   \
      _Pragma("unroll") for (int nn = 0; nn < 2; ++nn) {                                 \
        acc[(MH)*4 + mm][(NH)*2 + nn] = __builtin_amdgcn_mfma_f32_16x16x32_bf16(         \
            af[mm][0], bg[nn][0], acc[(MH)*4 + mm][(NH)*2 + nn], 0, 0, 0);               \
        acc[(MH)*4 + mm][(NH)*2 + nn] = __builtin_amdgcn_mfma_f32_16x16x32_bf16(         \
            af[mm][1], bg[nn][1], acc[(MH)*4 + mm][(NH)*2 + nn], 0, 0, 0);               \
      }                                                                                  \
    }                                                                                    \
    __builtin_amdgcn_s_setprio(0);                                                       \
  } while (0)

__global__ __launch_bounds__(512, 2) void gemm256_8ph(
    const unsigned short* __restrict__ A, const unsigned short* __restrict__ B,
    const float* __restrict__ bias, float* __restrict__ C, int M, int N, int K) {
  extern __shared__ char lds[];

  const int nbn = N >> 8;
  const int nwg = (M >> 8) * nbn;
  int bid = blockIdx.x;
  if ((nwg & 7) == 0) {  // XCD-aware swizzle (bijective when nwg%8==0)
    int q = nwg >> 3;
    bid = (bid & 7) * q + (bid >> 3);
  }
  const int bm = (bid / nbn) << 8;
  const int bn = (bid % nbn) << 8;

  const int tid = threadIdx.x;
  const int lane = tid & 63;
  const int wid = tid >> 6;
  const int wr = wid >> 2;  // 0..1
  const int wc = wid & 3;   // 0..3
  const int NT = K >> 6;    // K-tiles of 64

  // ---- staging: per-thread pre-swizzled global source pieces ----
  // LDS phys byte within unit: d = tid*16 + iload*8192 -> prow = d>>7, pcol=(tid&7)*16
  // logical col (elems) = (pcol ^ ((prow&7)<<4))/2 ; prow&7 == (tid>>3)&7
  const int colel = (((tid & 7) ^ ((tid >> 3) & 7)) << 3);  // 0..56 elems
  // A unit: tile row = iload*128 + mh*64 + (tid>>3)
  const unsigned short* a_g0 = A + (size_t)(bm + (tid >> 3)) * K + colel;
  // B unit: tile row = ((tid>>8)+iload*2)*64 + nh*32 + ((tid>>3)&31)
  const unsigned short* b_g0 = B + (size_t)(bn + ((tid >> 8) << 6) + ((tid >> 3) & 31)) * K + colel;

  auto STAGE_A = [&](int t, int mh, int buf) {
    const unsigned short* s = a_g0 + (size_t)(mh * 64) * K + t * 64;
    char* d = lds + buf * 65536 + mh * 16384 + tid * 16;
    __builtin_amdgcn_global_load_lds((gq_t*)s, (lq_t*)d, 16, 0, 0);
    __builtin_amdgcn_global_load_lds((gq_t*)(s + (size_t)128 * K), (lq_t*)(d + 8192), 16, 0, 0);
  };
  auto STAGE_B = [&](int t, int nh, int buf) {
    const unsigned short* s = b_g0 + (size_t)(nh * 32) * K + t * 64;
    char* d = lds + buf * 65536 + 32768 + nh * 16384 + tid * 16;
    __builtin_amdgcn_global_load_lds((gq_t*)s, (lq_t*)d, 16, 0, 0);
    __builtin_amdgcn_global_load_lds((gq_t*)(s + (size_t)128 * K), (lq_t*)(d + 8192), 16, 0, 0);
  };

  // ---- fragment read offsets (swizzled) ----
  const int i15 = lane & 15;
  const int qg = lane >> 4;                  // 0..3
  const int swz = (lane & 7) << 4;
  const int colp0 = (qg << 4) ^ swz;         // kk=0
  const int colp1 = ((qg << 4) | 64) ^ swz;  // kk=1
  const int aoff = wr * 8192 + i15 * 128;    // + mh*16384 + (m&3)*2048 + colp
  const int boff = 32768 + wc * 4096 + i15 * 128;  // + nh*16384 + (n&1)*2048 + colp

  f32x4 acc[8][4];
#pragma unroll
  for (int m = 0; m < 8; ++m)
#pragma unroll
    for (int n = 0; n < 4; ++n) acc[m][n] = (f32x4){0.f, 0.f, 0.f, 0.f};

  bf16x8 af[4][2], bg[2][2];

  auto LDA = [&](const char* base, int mh) {
    const char* p = base + mh * 16384 + aoff;
#pragma unroll
    for (int mm = 0; mm < 4; ++mm) {
      af[mm][0] = *(const bf16x8*)(p + mm * 2048 + colp0);
      af[mm][1] = *(const bf16x8*)(p + mm * 2048 + colp1);
    }
  };
  auto LDB = [&](const char* base, int nh) {
    const char* p = base + nh * 16384 + boff;
#pragma unroll
    for (int nn = 0; nn < 2; ++nn) {
      bg[nn][0] = *(const bf16x8*)(p + nn * 2048 + colp0);
      bg[nn][1] = *(const bf16x8*)(p + nn * 2048 + colp1);
    }
  };

  // ---- prologue: tile0's 4 units (oldest), then Am03(1), Bn23(1) ----
  STAGE_A(0, 0, 0); STAGE_A(0, 1, 0); STAGE_B(0, 0, 0); STAGE_B(0, 1, 0);
  STAGE_A(1, 0, 1); STAGE_B(1, 1, 1);
  WAITV4;   // retire tile0's 8 loads; {Am03(1),Bn23(1)} stay in flight
  BARRIER;

  // ---- main loop: 4 phases per K-tile ----
  for (int t = 0; t < NT; ++t) {
    const int cb = t & 1, ob = cb ^ 1;
    const char* cur = lds + cb * 65536;

    // P1 (Q: mh0 x nh0)
    if (t + 1 < NT) STAGE_A(t + 1, 1, ob);  // Am47(t+1): region dead since (t-1) end
    LDA(cur, 0);
    LDB(cur, 0);
    BARRIER;
    QUAD(0, 0);
    BARRIER;

    // P2 (Q: mh0 x nh1)
    if (t + 1 < NT) STAGE_B(t + 1, 0, ob);  // Bn01(t+1)
    LDB(cur, 1);
    BARRIER;
    QUAD(0, 1);
    BARRIER;

    // P3 (Q: mh1 x nh1)
    if (t + 2 < NT) STAGE_A(t + 2, 0, cb);  // Am03(t+2): cur's A-mh0 died at P2 barrier
    LDA(cur, 1);
    BARRIER;
    QUAD(1, 1);
    BARRIER;

    // P4 (Q: mh1 x nh0)
    if (t + 2 < NT) STAGE_B(t + 2, 1, cb);  // Bn23(t+2): cur's B-nh1 died at P3 barrier
    LDB(cur, 0);
    BARRIER;
    QUAD(1, 0);
    // boundary: retire all of tile t+1 (counted, not drained) — full drain once at NT-2
    if (t == NT - 2) { WAITV0; } else { WAITV4; }
    BARRIER;
  }

  // ---- epilogue: C/D map col=lane&15, row=(lane>>4)*4+reg ----
  const int r0 = bm + wr * 128 + ((lane >> 4) << 2);
  const int c0 = bn + wc * 64 + (lane & 15);
  float bv[4];
#pragma unroll
  for (int n = 0; n < 4; ++n) bv[n] = bias[c0 + n * 16];
#pragma unroll
  for (int m = 0; m < 8; ++m) {
#pragma unroll
    for (int r = 0; r < 4; ++r) {
      float* crow = C + (size_t)(r0 + m * 16 + r) * N + c0;
#pragma unroll
      for (int n = 0; n < 4; ++n) crow[n * 16] = acc[m][n][r] + bv[n];
    }
  }
}

// ---------- fallback: fp32 tiled (odd shapes / tiny ws) ----------
__global__ void gemm_fallback_kernel(const float* __restrict__ X, const float* __restrict__ W,
                                     const float* __restrict__ scale, const float* __restrict__ bias,
                                     float* __restrict__ out, int M, int N, int K) {
  __shared__ float as[64][33];
  __shared__ float bs[64][33];
  int tx = threadIdx.x & 15, ty = threadIdx.x >> 4;
  int brow = blockIdx.y * 64, bcol = blockIdx.x * 64;
  float acc[4][4] = {};
  for (int k0 = 0; k0 < K; k0 += 32) {
    int kw = (K - k0 < 32) ? (K - k0) : 32;
    for (int i = 0; i < 8; ++i) {
      int idx = (int)threadIdx.x + i * 256;
      int r = idx >> 5, c = idx & 31;
      int ga = brow + r, gb = bcol + r;
      as[r][c] = (ga < M && c < kw) ? X[(size_t)ga * K + k0 + c] : 0.f;
      bs[r][c] = (gb < N && c < kw) ? W[(size_t)gb * K + k0 + c] * scale[gb] : 0.f;
    }
    __syncthreads();
    for (int k = 0; k < 32; ++k)
#pragma unroll
      for (int i = 0; i < 4; ++i)
#pragma unroll
        for (int j = 0; j < 4; ++j)
          acc[i][j] += as[ty * 4 + i][k] * bs[tx * 4 + j][k];
    __syncthreads();
  }
  for (int i = 0; i < 4; ++i) {
    int r = brow + ty * 4 + i;
    if (r >= M) continue;
    for (int j = 0; j < 4; ++j) {
      int c = bcol + tx * 4 + j;
      if (c < N) out[(size_t)r * N + c] = acc[i][j] + bias[c];
    }
  }
}

extern "C" void kernel_launch(void* const* d_in, const int* in_sizes, int n_in,
                              void* d_out, int out_size, void* d_ws, size_t ws_size,
                              hipStream_t stream) {
  const float* x     = (const float*)d_in[0];
  const float* w     = (const float*)d_in[1];
  const float* scale = (const float*)d_in[2];
  const float* bias  = (const float*)d_in[3];
  float* out = (float*)d_out;

  const long N = in_sizes[2];            // D_OUT
  const long K = in_sizes[1] / N;        // D_IN
  const long M = (long)in_sizes[0] / K;  // B*S

  const size_t need = ((size_t)M * K + (size_t)N * K) * sizeof(unsigned short);
  const long NT = K / 64;
  const bool ok = (ws_size >= need) && (M % 256 == 0) && (N % 256 == 0) &&
                  (K % 64 == 0) && (NT >= 3);

  if (ok) {
    unsigned short* xa = (unsigned short*)d_ws;
    unsigned short* wb = xa + (size_t)M * K;
    cvt_x_kernel<<<2048, 256, 0, stream>>>(x, (ushort8*)xa, (int)((size_t)M * K / 8));
    cvt_w_kernel<<<1024, 256, 0, stream>>>(w, scale, (ushort8*)wb, (int)((size_t)N * K / 8), (int)(K / 8));

    static int attr_done = 0;  // idempotent host-side attribute (not a stream op)
    (void)hipFuncSetAttribute((const void*)gemm256_8ph,
                              hipFuncAttributeMaxDynamicSharedMemorySize, 131072);
    int nwg = (int)((M / 256) * (N / 256));
    gemm256_8ph<<<nwg, 512, 131072, stream>>>(xa, wb, bias, out, (int)M, (int)N, (int)K);
    (void)attr_done;
  } else {
    dim3 grid((unsigned)((N + 63) / 64), (unsigned)((M + 63) / 64));
    gemm_fallback_kernel<<<grid, 256, 0, stream>>>(x, w, scale, bias, out, (int)M, (int)N, (int)K);
  }
}

// Round 3
// 173.622 us; speedup vs baseline: 1.3951x; 1.0135x over previous
//
#include <hip/hip_runtime.h>

typedef __attribute__((ext_vector_type(8))) __bf16 bf16x8;
typedef __attribute__((ext_vector_type(4))) float f32x4;
typedef __attribute__((ext_vector_type(8))) unsigned short ushort8;
typedef const __attribute__((address_space(1))) unsigned int gq_t;
typedef __attribute__((address_space(3))) unsigned int lq_t;

// RNE float -> bf16 (finite inputs)
__device__ __forceinline__ unsigned short f2bf(float f) {
  unsigned int u = __builtin_bit_cast(unsigned int, f);
  u += 0x7fffu + ((u >> 16) & 1u);
  return (unsigned short)(u >> 16);
}

// ---------------- convert x: fp32 [M*K] -> bf16 ----------------
__global__ void cvt_x_kernel(const float* __restrict__ x, ushort8* __restrict__ o, int n8) {
  int stride = gridDim.x * blockDim.x;
  for (int i = blockIdx.x * blockDim.x + threadIdx.x; i < n8; i += stride) {
    const float4* p = (const float4*)(x) + 2 * (size_t)i;
    float4 v0 = p[0], v1 = p[1];
    ushort8 r;
    r[0] = f2bf(v0.x); r[1] = f2bf(v0.y); r[2] = f2bf(v0.z); r[3] = f2bf(v0.w);
    r[4] = f2bf(v1.x); r[5] = f2bf(v1.y); r[6] = f2bf(v1.z); r[7] = f2bf(v1.w);
    o[i] = r;
  }
}

// ------- convert weight: fp32 [N][K] * scale[n] -> bf16 --------
__global__ void cvt_w_kernel(const float* __restrict__ w, const float* __restrict__ scale,
                             ushort8* __restrict__ o, int n8, int k8) {
  int stride = gridDim.x * blockDim.x;
  for (int i = blockIdx.x * blockDim.x + threadIdx.x; i < n8; i += stride) {
    float s = scale[i / k8];
    const float4* p = (const float4*)(w) + 2 * (size_t)i;
    float4 v0 = p[0], v1 = p[1];
    ushort8 r;
    r[0] = f2bf(v0.x * s); r[1] = f2bf(v0.y * s); r[2] = f2bf(v0.z * s); r[3] = f2bf(v0.w * s);
    r[4] = f2bf(v1.x * s); r[5] = f2bf(v1.y * s); r[6] = f2bf(v1.z * s); r[7] = f2bf(v1.w * s);
    o[i] = r;
  }
}

// =================== 256x256 8-phase GEMM ===================
// C = A * B^T + bias.  A: bf16 [M][K], B: bf16 [N][K], C: fp32 [M][N].
// 8 waves (2 wr x 4 wc), BK=64, 128 KiB dynamic LDS:
//   per buffer (64 KiB): [A-mh0 16K][A-mh1 16K][B-nh0 16K][B-nh1 16K]
// XOR swizzle within each 128B row: byte ^= ((row&7)<<4), applied on the
// pre-swizzled GLOBAL source (linear LDS dest for global_load_lds) + on reads.
// Per K-tile: 4 phases {ds_reads; stage-issue; barrier; MFMA x16; barrier},
// B halves both held in regs (no re-read; P4 has zero ds_reads).
// vmcnt(4) once per K-tile boundary (2 units stay in flight), drain at NT-2.

#define FENCE asm volatile("" ::: "memory")
#define BARRIER do { FENCE; __builtin_amdgcn_s_barrier(); FENCE; } while (0)
#define WAITV4 asm volatile("s_waitcnt vmcnt(4)" ::: "memory")
#define WAITV0 asm volatile("s_waitcnt vmcnt(0)" ::: "memory")

// kk-outer: 8 independent acc chains between dependent MFMA reuses
#define QUAD(MH, NH)                                                                     \
  do {                                                                                   \
    __builtin_amdgcn_s_setprio(1);                                                       \
    _Pragma("unroll") for (int k = 0; k < 2; ++k) {                                      \
      _Pragma("unroll") for (int mm = 0; mm < 4; ++mm) {                                 \
        _Pragma("unroll") for (int nn = 0; nn < 2; ++nn) {                               \
          acc[(MH)*4 + mm][(NH)*2 + nn] = __builtin_amdgcn_mfma_f32_16x16x32_bf16(       \
              af[mm][k], bg[NH][nn][k], acc[(MH)*4 + mm][(NH)*2 + nn], 0, 0, 0);         \
        }                                                                                \
      }                                                                                  \
    }                                                                                    \
    __builtin_amdgcn_s_setprio(0);                                                       \
  } while (0)

__global__ __launch_bounds__(512, 2) void gemm256_8ph(
    const unsigned short* __restrict__ A, const unsigned short* __restrict__ B,
    const float* __restrict__ bias, float* __restrict__ C, int M, int N, int K) {
  extern __shared__ char lds[];

  const int nbn = N >> 8;
  const int nwg = (M >> 8) * nbn;
  int bid = blockIdx.x;
  if ((nwg & 7) == 0) {  // XCD-aware swizzle (bijective when nwg%8==0)
    int q = nwg >> 3;
    bid = (bid & 7) * q + (bid >> 3);
  }
  const int bm = (bid / nbn) << 8;
  const int bn = (bid % nbn) << 8;

  const int tid = threadIdx.x;
  const int lane = tid & 63;
  const int wid = tid >> 6;
  const int wr = wid >> 2;  // 0..1
  const int wc = wid & 3;   // 0..3
  const int NT = K >> 6;    // K-tiles of 64

  // ---- staging: per-thread pre-swizzled global source pieces ----
  // LDS phys byte within unit: d = tid*16 + iload*8192 -> prow = d>>7, pcol=(tid&7)*16
  // logical col (elems) = (pcol ^ ((prow&7)<<4))/2 ; prow&7 == (tid>>3)&7
  const int colel = (((tid & 7) ^ ((tid >> 3) & 7)) << 3);  // 0..56 elems
  // A unit: tile row = iload*128 + mh*64 + (tid>>3)
  const unsigned short* a_g0 = A + (size_t)(bm + (tid >> 3)) * K + colel;
  // B unit: tile row = ((tid>>8)+iload*2)*64 + nh*32 + ((tid>>3)&31)
  const unsigned short* b_g0 = B + (size_t)(bn + ((tid >> 8) << 6) + ((tid >> 3) & 31)) * K + colel;

  auto STAGE_A = [&](int t, int mh, int buf) {
    const unsigned short* s = a_g0 + (size_t)(mh * 64) * K + t * 64;
    char* d = lds + buf * 65536 + mh * 16384 + tid * 16;
    __builtin_amdgcn_global_load_lds((gq_t*)s, (lq_t*)d, 16, 0, 0);
    __builtin_amdgcn_global_load_lds((gq_t*)(s + (size_t)128 * K), (lq_t*)(d + 8192), 16, 0, 0);
  };
  auto STAGE_B = [&](int t, int nh, int buf) {
    const unsigned short* s = b_g0 + (size_t)(nh * 32) * K + t * 64;
    char* d = lds + buf * 65536 + 32768 + nh * 16384 + tid * 16;
    __builtin_amdgcn_global_load_lds((gq_t*)s, (lq_t*)d, 16, 0, 0);
    __builtin_amdgcn_global_load_lds((gq_t*)(s + (size_t)128 * K), (lq_t*)(d + 8192), 16, 0, 0);
  };

  // ---- fragment read offsets (swizzled) ----
  const int i15 = lane & 15;
  const int qg = lane >> 4;                  // 0..3
  const int swz = (lane & 7) << 4;
  const int colp0 = (qg << 4) ^ swz;         // kk=0
  const int colp1 = ((qg << 4) | 64) ^ swz;  // kk=1
  const int aoff = wr * 8192 + i15 * 128;    // + mh*16384 + (m&3)*2048 + colp
  const int boff = 32768 + wc * 4096 + i15 * 128;  // + nh*16384 + (n&1)*2048 + colp

  f32x4 acc[8][4];
#pragma unroll
  for (int m = 0; m < 8; ++m)
#pragma unroll
    for (int n = 0; n < 4; ++n) acc[m][n] = (f32x4){0.f, 0.f, 0.f, 0.f};

  bf16x8 af[4][2];      // current A half (mh), [mm][kk]
  bf16x8 bg[2][2][2];   // BOTH B halves resident: [nh][nn][kk]

  auto LDA = [&](const char* base, int mh) {
    const char* p = base + mh * 16384 + aoff;
#pragma unroll
    for (int mm = 0; mm < 4; ++mm) {
      af[mm][0] = *(const bf16x8*)(p + mm * 2048 + colp0);
      af[mm][1] = *(const bf16x8*)(p + mm * 2048 + colp1);
    }
  };
  auto LDB = [&](const char* base, int nh) {
    const char* p = base + nh * 16384 + boff;
#pragma unroll
    for (int nn = 0; nn < 2; ++nn) {
      bg[nh][nn][0] = *(const bf16x8*)(p + nn * 2048 + colp0);
      bg[nh][nn][1] = *(const bf16x8*)(p + nn * 2048 + colp1);
    }
  };

  // ---- prologue: tile0's 4 units (oldest), then Am47(1), Bn23(1) ----
  STAGE_A(0, 0, 0); STAGE_A(0, 1, 0); STAGE_B(0, 0, 0); STAGE_B(0, 1, 0);
  STAGE_A(1, 1, 1); STAGE_B(1, 1, 1);
  WAITV4;   // retire tile0's 8 loads; 2 units of tile1 stay in flight
  BARRIER;

  // ---- main loop: 4 phases per K-tile ----
  for (int t = 0; t < NT; ++t) {
    const int cb = t & 1, ob = cb ^ 1;
    const char* cur = lds + cb * 65536;

    // P1 (Q: mh0 x nh0) — reads A-mh0 + B-nh0
    LDA(cur, 0);
    LDB(cur, 0);
    if (t + 1 < NT) STAGE_A(t + 1, 0, ob);  // Am03(t+1)
    BARRIER;
    QUAD(0, 0);
    BARRIER;

    // P2 (Q: mh0 x nh1) — reads B-nh1 (af persists)
    LDB(cur, 1);
    if (t + 1 < NT) STAGE_B(t + 1, 0, ob);  // Bn01(t+1)
    BARRIER;
    QUAD(0, 1);
    BARRIER;

    // P3 (Q: mh1 x nh1) — reads A-mh1 (bg persists)
    LDA(cur, 1);
    if (t + 2 < NT) STAGE_A(t + 2, 1, cb);  // Am47(t+2): cur A-mh0 dead since P1-end
    BARRIER;
    QUAD(1, 1);
    BARRIER;

    // P4 (Q: mh1 x nh0) — zero ds_reads (both operand sets in regs)
    if (t + 2 < NT) STAGE_B(t + 2, 1, cb);  // Bn23(t+2): cur B-nh1 dead since P2-end
    BARRIER;
    QUAD(1, 0);
    // boundary: retire all of tile t+1 (counted, not drained) — full drain at NT-2
    if (t == NT - 2) { WAITV0; } else { WAITV4; }
    BARRIER;
  }

  // ---- epilogue: C/D map col=lane&15, row=(lane>>4)*4+reg ----
  const int r0 = bm + wr * 128 + ((lane >> 4) << 2);
  const int c0 = bn + wc * 64 + (lane & 15);
  float bv[4];
#pragma unroll
  for (int n = 0; n < 4; ++n) bv[n] = bias[c0 + n * 16];
#pragma unroll
  for (int m = 0; m < 8; ++m) {
#pragma unroll
    for (int r = 0; r < 4; ++r) {
      float* crow = C + (size_t)(r0 + m * 16 + r) * N + c0;
#pragma unroll
      for (int n = 0; n < 4; ++n) crow[n * 16] = acc[m][n][r] + bv[n];
    }
  }
}

// ---------- fallback: fp32 tiled (odd shapes / tiny ws) ----------
__global__ void gemm_fallback_kernel(const float* __restrict__ X, const float* __restrict__ W,
                                     const float* __restrict__ scale, const float* __restrict__ bias,
                                     float* __restrict__ out, int M, int N, int K) {
  __shared__ float as[64][33];
  __shared__ float bs[64][33];
  int tx = threadIdx.x & 15, ty = threadIdx.x >> 4;
  int brow = blockIdx.y * 64, bcol = blockIdx.x * 64;
  float acc[4][4] = {};
  for (int k0 = 0; k0 < K; k0 += 32) {
    int kw = (K - k0 < 32) ? (K - k0) : 32;
    for (int i = 0; i < 8; ++i) {
      int idx = (int)threadIdx.x + i * 256;
      int r = idx >> 5, c = idx & 31;
      int ga = brow + r, gb = bcol + r;
      as[r][c] = (ga < M && c < kw) ? X[(size_t)ga * K + k0 + c] : 0.f;
      bs[r][c] = (gb < N && c < kw) ? W[(size_t)gb * K + k0 + c] * scale[gb] : 0.f;
    }
    __syncthreads();
    for (int k = 0; k < 32; ++k)
#pragma unroll
      for (int i = 0; i < 4; ++i)
#pragma unroll
        for (int j = 0; j < 4; ++j)
          acc[i][j] += as[ty * 4 + i][k] * bs[tx * 4 + j][k];
    __syncthreads();
  }
  for (int i = 0; i < 4; ++i) {
    int r = brow + ty * 4 + i;
    if (r >= M) continue;
    for (int j = 0; j < 4; ++j) {
      int c = bcol + tx * 4 + j;
      if (c < N) out[(size_t)r * N + c] = acc[i][j] + bias[c];
    }
  }
}

extern "C" void kernel_launch(void* const* d_in, const int* in_sizes, int n_in,
                              void* d_out, int out_size, void* d_ws, size_t ws_size,
                              hipStream_t stream) {
  const float* x     = (const float*)d_in[0];
  const float* w     = (const float*)d_in[1];
  const float* scale = (const float*)d_in[2];
  const float* bias  = (const float*)d_in[3];
  float* out = (float*)d_out;

  const long N = in_sizes[2];            // D_OUT
  const long K = in_sizes[1] / N;        // D_IN
  const long M = (long)in_sizes[0] / K;  // B*S

  const size_t need = ((size_t)M * K + (size_t)N * K) * sizeof(unsigned short);
  const long NT = K / 64;
  const bool ok = (ws_size >= need) && (M % 256 == 0) && (N % 256 == 0) &&
                  (K % 64 == 0) && (NT >= 3);

  if (ok) {
    unsigned short* xa = (unsigned short*)d_ws;
    unsigned short* wb = xa + (size_t)M * K;
    cvt_x_kernel<<<2048, 256, 0, stream>>>(x, (ushort8*)xa, (int)((size_t)M * K / 8));
    cvt_w_kernel<<<1024, 256, 0, stream>>>(w, scale, (ushort8*)wb, (int)((size_t)N * K / 8), (int)(K / 8));

    (void)hipFuncSetAttribute((const void*)gemm256_8ph,
                              hipFuncAttributeMaxDynamicSharedMemorySize, 131072);
    int nwg = (int)((M / 256) * (N / 256));
    gemm256_8ph<<<nwg, 512, 131072, stream>>>(xa, wb, bias, out, (int)M, (int)N, (int)K);
  } else {
    dim3 grid((unsigned)((N + 63) / 64), (unsigned)((M + 63) / 64));
    gemm_fallback_kernel<<<grid, 256, 0, stream>>>(x, w, scale, bias, out, (int)M, (int)N, (int)K);
  }
}